// Round 12
// baseline (155.495 us; speedup 1.0000x reference)
//
#include <hip/hip_runtime.h>
#include <math.h>

#define IN_CH 128
#define OUT_CH 64
#define NEG_SLOPE 0.2f
#define CAP 64           // slots per node; mean degree 16, P(deg>64) ~ 1e-16
#define BSHIFT 8         // 256 nodes per dst-bucket -> bucket id = dst >> 8
#define BS 256           // bucket width (nodes)
#define CHUNK_EDGES 4096 // edges per bucket-role block (256 thr x 16)
#define AGG_REP 2        // DIAGNOSTIC: k_agg body repeated; total-delta == 1x k_agg,
                         // and the ~2x-dur dispatch surfaces above the 44us fills
                         // to finally yield counters for the aggregation phase.

typedef long long ll2 __attribute__((ext_vector_type(2)));
typedef int i4v __attribute__((ext_vector_type(4)));

// ---------- bf16 helpers ----------
__device__ __forceinline__ unsigned short f2bf(float f) {
    unsigned u = __float_as_uint(f);
    unsigned r = (u + 0x7FFFu + ((u >> 16) & 1u)) >> 16;   // round-nearest-even
    return (unsigned short)r;
}

// ---------- direct global->LDS 16B copy (lane i writes ldsbase + i*16) ----------
__device__ __forceinline__ void gload_lds16(const void* g, void* l) {
    __builtin_amdgcn_global_load_lds(
        (const __attribute__((address_space(1))) void*)g,
        (__attribute__((address_space(3))) void*)l, 16, 0, 0);
}

// ---------- edge dtype sniff: int64 little-endian => odd int32 words are 0 ----------
__device__ __forceinline__ bool sniff_is64(const void* edges) {
    const unsigned* up = (const unsigned*)edges;
    bool is64 = true;
#pragma unroll
    for (int k = 0; k < 16; k++) is64 = is64 && (up[2 * k + 1] == 0u);
    return is64;
}

// ---------- K1: bucket blocks (bid<nbkt) overlapped with mm blocks ----------
// (R10-passed structure, unchanged. R11's cooperative fusion FAILED: cooperative
// launch is incompatible with the harness's graph capture -- kernel never ran,
// out stayed zero-memset. Reverted; this round instruments k_agg instead.)
__global__ __launch_bounds__(256) void k_mm_bkt(
        const float* __restrict__ x, const float* __restrict__ W,
        const float* __restrict__ att, unsigned short* __restrict__ h16,
        float* __restrict__ asrc, float* __restrict__ adst, int N,
        const void* __restrict__ edges, int E, int nbkt,
        int2* __restrict__ bucket, int bcap, int* __restrict__ bucket_cnt) {
    __shared__ float Xs[64 * IN_CH];   // 32 KB x tile (mm); bucket role aliases 2KB
    int t = threadIdx.x;
    int bid = blockIdx.x;

    if (bid < nbkt) {
        // ----- bucket role: scatter 4096 edges into per-256-node-range buckets -----
        int* lcur = (int*)Xs;          // [256]
        int* lbase = lcur + 256;       // [256]
        lcur[t] = 0;
        __syncthreads();

        int base = bid * CHUNK_EDGES + t * 16;
        bool is64 = sniff_is64(edges);
        int sv[16], dv[16], rr[16];
        int nv = E - base;
        if (nv > 16) nv = 16;
        if (nv < 0) nv = 0;
        if (nv == 16) {
            if (is64) {
                const ll2* ps = (const ll2*)((const long long*)edges + base);
                const ll2* pd = (const ll2*)((const long long*)edges + (size_t)E + base);
#pragma unroll
                for (int i = 0; i < 8; i++) {
                    ll2 v = __builtin_nontemporal_load(ps + i);
                    sv[2 * i] = (int)v.x; sv[2 * i + 1] = (int)v.y;
                }
#pragma unroll
                for (int i = 0; i < 8; i++) {
                    ll2 w = __builtin_nontemporal_load(pd + i);
                    dv[2 * i] = (int)w.x; dv[2 * i + 1] = (int)w.y;
                }
            } else {
                const i4v* ps = (const i4v*)((const int*)edges + base);
                const i4v* pd = (const i4v*)((const int*)edges + E + base);
#pragma unroll
                for (int i = 0; i < 4; i++) {
                    i4v v = __builtin_nontemporal_load(ps + i);
                    sv[4 * i] = v.x; sv[4 * i + 1] = v.y;
                    sv[4 * i + 2] = v.z; sv[4 * i + 3] = v.w;
                }
#pragma unroll
                for (int i = 0; i < 4; i++) {
                    i4v w = __builtin_nontemporal_load(pd + i);
                    dv[4 * i] = w.x; dv[4 * i + 1] = w.y;
                    dv[4 * i + 2] = w.z; dv[4 * i + 3] = w.w;
                }
            }
        } else {
            for (int i = 0; i < 16; i++) {
                if (i < nv) {
                    if (is64) {
                        sv[i] = (int)((const long long*)edges)[base + i];
                        dv[i] = (int)((const long long*)edges)[(size_t)E + base + i];
                    } else {
                        sv[i] = ((const int*)edges)[base + i];
                        dv[i] = ((const int*)edges)[E + base + i];
                    }
                } else { sv[i] = 0; dv[i] = 0; }
            }
        }
        // LDS-cursor positions (order within bucket irrelevant downstream)
#pragma unroll
        for (int i = 0; i < 16; i++)
            if (i < nv) rr[i] = atomicAdd(&lcur[(unsigned)dv[i] >> BSHIFT], 1);
        __syncthreads();
        // one device atomic per non-empty (block,bucket)
        if (t < nbkt && lcur[t] > 0) lbase[t] = atomicAdd(bucket_cnt + t, lcur[t]);
        __syncthreads();
        // place edges (contiguous run per bucket)
#pragma unroll
        for (int i = 0; i < 16; i++) {
            if (i < nv) {
                int b = (unsigned)dv[i] >> BSHIFT;
                bucket[(size_t)b * bcap + lbase[b] + rr[i]] = make_int2(sv[i], dv[i]);
            }
        }
        return;
    }

    // ----- mm role: 64 nodes/block; x tile staged in LDS; W straight from global -----
    int id = bid - nbkt;
    {
        int wv_ = t >> 6;          // wave id 0..3
        int lane = t & 63;
        int col16 = (lane & 31) * 4;                   // 16B column chunk (floats)
#pragma unroll
        for (int i = 0; i < 8; i++) {
            int seg = wv_ * 8 + i;                     // 1KB segment = 2 rows
            int row = id * 64 + seg * 2 + (lane >> 5);
            row = min(row, N - 1);                     // tail clamp (dup row N-1)
            gload_lds16(&x[(size_t)row * IN_CH + col16], &Xs[seg * 256]);
        }
    }
    int cg = t & 15, g = t >> 4;
    float4 att_d = *(const float4*)&att[cg * 4];        // dst half: att[0:64]
    float4 att_s = *(const float4*)&att[64 + cg * 4];   // src half: att[64:128]
    __syncthreads();   // drains vmcnt (global_load_lds)

    int n0 = id * 64 + g * 4;

    float4 acc[4];
#pragma unroll
    for (int m = 0; m < 4; m++) acc[m] = make_float4(0.f, 0.f, 0.f, 0.f);

#pragma unroll 2
    for (int k4 = 0; k4 < IN_CH / 4; k4++) {
        float4 xv[4];
#pragma unroll
        for (int m = 0; m < 4; m++)
            xv[m] = *(const float4*)&Xs[(g * 4 + m) * IN_CH + k4 * 4];
        float4 wv[4];
#pragma unroll
        for (int j = 0; j < 4; j++)
            wv[j] = *(const float4*)&W[(k4 * 4 + j) * OUT_CH + cg * 4];
#pragma unroll
        for (int m = 0; m < 4; m++) {
            acc[m].x = fmaf(xv[m].x, wv[0].x, acc[m].x);
            acc[m].y = fmaf(xv[m].x, wv[0].y, acc[m].y);
            acc[m].z = fmaf(xv[m].x, wv[0].z, acc[m].z);
            acc[m].w = fmaf(xv[m].x, wv[0].w, acc[m].w);
            acc[m].x = fmaf(xv[m].y, wv[1].x, acc[m].x);
            acc[m].y = fmaf(xv[m].y, wv[1].y, acc[m].y);
            acc[m].z = fmaf(xv[m].y, wv[1].z, acc[m].z);
            acc[m].w = fmaf(xv[m].y, wv[1].w, acc[m].w);
            acc[m].x = fmaf(xv[m].z, wv[2].x, acc[m].x);
            acc[m].y = fmaf(xv[m].z, wv[2].y, acc[m].y);
            acc[m].z = fmaf(xv[m].z, wv[2].z, acc[m].z);
            acc[m].w = fmaf(xv[m].z, wv[2].w, acc[m].w);
            acc[m].x = fmaf(xv[m].w, wv[3].x, acc[m].x);
            acc[m].y = fmaf(xv[m].w, wv[3].y, acc[m].y);
            acc[m].z = fmaf(xv[m].w, wv[3].z, acc[m].z);
            acc[m].w = fmaf(xv[m].w, wv[3].w, acc[m].w);
        }
    }

#pragma unroll
    for (int m = 0; m < 4; m++) {
        int node = n0 + m;
        if (node < N) {
            ushort4 hv;
            hv.x = f2bf(acc[m].x);
            hv.y = f2bf(acc[m].y);
            hv.z = f2bf(acc[m].z);
            hv.w = f2bf(acc[m].w);
            *(ushort4*)&h16[(size_t)node * OUT_CH + cg * 4] = hv;
        }
        float pd = acc[m].x * att_d.x + acc[m].y * att_d.y +
                   acc[m].z * att_d.z + acc[m].w * att_d.w;
        float ps = acc[m].x * att_s.x + acc[m].y * att_s.y +
                   acc[m].z * att_s.z + acc[m].w * att_s.w;
#pragma unroll
        for (int msk = 1; msk < 16; msk <<= 1) {
            pd += __shfl_xor(pd, msk, 64);
            ps += __shfl_xor(ps, msk, 64);
        }
        if (cg == 0 && node < N) { adst[node] = pd; asrc[node] = ps; }
    }
}

// ---------- K2: exclusive-bucket count+scatter (zero per-edge global atomics) -------
__global__ __launch_bounds__(256) void k_cs(
        const int2* __restrict__ bucket, int bcap,
        const int* __restrict__ bucket_cnt, int* __restrict__ counts,
        int* __restrict__ slots, int* __restrict__ oflow_cnt,
        int2* __restrict__ oflow, int N) {
    __shared__ int lcnt[256];
    int t = threadIdx.x;
    int id = blockIdx.x;
    int lo = id << BSHIFT;
    lcnt[t] = 0;
    __syncthreads();
    int cnt = bucket_cnt[id];
    const int2* mybkt = bucket + (size_t)id * bcap;
    for (int idx = t; idx < cnt; idx += 256) {
        int2 e = mybkt[idx];                       // coalesced 2KB per sweep
        int r = atomicAdd(&lcnt[e.y - lo], 1);     // LDS atomic
        if (r < CAP) {
            slots[((size_t)e.y << 6) + r] = e.x;   // exclusive, written once
        } else {
            int p2 = atomicAdd(oflow_cnt, 1);      // statistically never
            oflow[p2] = e;
        }
    }
    __syncthreads();
    int node = lo + t;
    if (node < N) counts[node] = lcnt[t];          // coalesced, line-aligned
}

// ---------- K3: softmax-aggregate, DIAGNOSTIC x2 repeat ----------
// Body is idempotent (reads k1/k2 outputs, writes only out), so repeating it is
// correctness-neutral. The "memory" clobber forces real reloads each rep (no CSE),
// so dispatch duration ~= AGG_REP x true cost: total-delta vs R10 measures k_agg
// exactly, and the dispatch surfaces above the 44us harness fills for counters.
__global__ __launch_bounds__(256) void k_agg(const unsigned short* __restrict__ h16,
                                             const int* __restrict__ slots,
                                             const int* __restrict__ counts,
                                             const int* __restrict__ oflow_cnt,
                                             const int2* __restrict__ oflow,
                                             const float* __restrict__ asrc,
                                             const float* __restrict__ adst,
                                             const float* __restrict__ bias,
                                             float* __restrict__ out, int N) {
    __shared__ float2 stage[4][64];   // wave-private
    int lane = threadIdx.x & 63;
    int wid = threadIdx.x >> 6;
    int node = blockIdx.x * 4 + wid;
    if (node >= N) return;
    int half = lane >> 5;
    int ch2 = (lane & 31) * 2;

    for (int rep = 0; rep < AGG_REP; rep++) {
        asm volatile("" ::: "memory");   // force reloads: each rep does real work

        float aD = adst[node];
        float a = aD + asrc[node];
        a = a > 0.f ? a : NEG_SLOPE * a;
        float w_self = __expf(a);
        unsigned hv = *(const unsigned*)&h16[(size_t)node * OUT_CH + ch2];
        float wse = half ? 0.f : w_self;
        float accx = wse * __uint_as_float(hv << 16);
        float accy = wse * __uint_as_float(hv & 0xFFFF0000u);

        int c = counts[node];           // true degree (may exceed CAP)
        int cs = min(c, CAP);
        int sv = 0;
        float wv = 0.f;
        if (lane < cs) {
            sv = slots[((size_t)node << 6) + lane];   // coalesced 256B
            float av = aD + asrc[sv];                 // parallel gather (L2-hot)
            av = av > 0.f ? av : NEG_SLOPE * av;
            wv = __expf(av);
        }
        float esum_lane = wv;
        stage[wid][lane] = make_float2(__int_as_float(sv), wv);

        for (int j = 0; j < cs; j += 16) {
#pragma unroll
            for (int k = 0; k < 8; k++) {
                float2 p = stage[wid][j + 2 * k + half];   // wave-synchronous LDS
                int s = __float_as_int(p.x);
                unsigned v = *(const unsigned*)&h16[((size_t)s << 6) + ch2];
                accx = fmaf(p.y, __uint_as_float(v << 16), accx);
                accy = fmaf(p.y, __uint_as_float(v & 0xFFFF0000u), accy);
            }
        }
        // combine half-waves (even rows in lanes 0-31, odd rows in 32-63)
        accx += __shfl_xor(accx, 32, 64);
        accy += __shfl_xor(accy, 32, 64);
#pragma unroll
        for (int m = 32; m >= 1; m >>= 1) esum_lane += __shfl_xor(esum_lane, m, 64);
        float esum = esum_lane + w_self;

        // cold overflow path (oc == 0 for this input; correct if not)
        int oc = *oflow_cnt;
        if (oc > 0) {
            for (int i = 0; i < oc; i++) {
                int2 e = oflow[i];
                if (e.y == node) {
                    float av = aD + asrc[e.x];
                    av = av > 0.f ? av : NEG_SLOPE * av;
                    float w = __expf(av);
                    esum += w;
                    unsigned v = *(const unsigned*)&h16[((size_t)e.x << 6) + ch2];
                    accx = fmaf(w, __uint_as_float(v << 16), accx);
                    accy = fmaf(w, __uint_as_float(v & 0xFFFF0000u), accy);
                }
            }
        }

        float inv = 1.f / (esum + 1e-16f);
        float2 bv = *(const float2*)&bias[ch2];
        float vx = accx * inv + bv.x;
        float vy = accy * inv + bv.y;
        float ss = vx * vx + vy * vy;
#pragma unroll
        for (int m = 16; m >= 1; m >>= 1) ss += __shfl_xor(ss, m, 64);   // within half
        float rinv = 1.f / fmaxf(sqrtf(ss), 1e-12f);
        if (!half)
            *(float2*)&out[(size_t)node * OUT_CH + ch2] =
                make_float2(vx * rinv, vy * rinv);
    }
}

extern "C" void kernel_launch(void* const* d_in, const int* in_sizes, int n_in,
                              void* d_out, int out_size, void* d_ws, size_t ws_size,
                              hipStream_t stream) {
    const float* x    = (const float*)d_in[0];
    const void*  edges = d_in[1];
    const float* W    = (const float*)d_in[2];
    const float* att  = (const float*)d_in[3];
    const float* bias = (const float*)d_in[4];
    float* out = (float*)d_out;

    const int N = in_sizes[0] / IN_CH;
    const int E = in_sizes[1] / 2;
    const int NBKT = (N + BS - 1) / BS;                  // 196 buckets (<=256)
    const int MMB = (N + 63) / 64;                       // 782 mm blocks
    const int BKB = (E + CHUNK_EDGES - 1) / CHUNK_EDGES; // 196 bucket blocks
    const int K1B = (BKB > NBKT ? BKB : NBKT);
    const int bcap = E / NBKT + 2048;                    // >30 sigma headroom

    char* ws = (char*)d_ws;
    size_t off = 0;
    auto alloc = [&](size_t bytes) -> void* {
        void* p = ws + off;
        off += bytes;
        off = (off + 255) & ~(size_t)255;
        return p;
    };
    // control block (memset target): bucket_cnt[256] | oflow_cnt @256
    int*            ctrl     = (int*)alloc(320 * 4);
    int*            counts   = (int*)alloc((size_t)N * 4);         // fully written by k2
    int*            slots    = (int*)alloc((size_t)N * CAP * 4);   // 12.8 MB
    int2*           oflow    = (int2*)alloc((size_t)65536 * 8);    // stat-impossible
    unsigned short* h16      = (unsigned short*)alloc((size_t)N * OUT_CH * 2);
    float*          asrc     = (float*)alloc((size_t)N * 4);
    float*          adst     = (float*)alloc((size_t)N * 4);
    int2*           bucket   = (int2*)alloc((size_t)NBKT * bcap * 8);  // ~9.6 MB
    int*            bucket_cnt = ctrl;
    int*            oflow_cnt  = ctrl + 256;

    hipMemsetAsync(ctrl, 0, 320 * 4, stream);
    k_mm_bkt<<<K1B + MMB, 256, 0, stream>>>(x, W, att, h16, asrc, adst, N,
                                            edges, E, NBKT, bucket, bcap,
                                            bucket_cnt);
    k_cs<<<NBKT, 256, 0, stream>>>(bucket, bcap, bucket_cnt, counts,
                                   slots, oflow_cnt, oflow, N);
    k_agg<<<(N + 3) / 4, 256, 0, stream>>>(h16, slots, counts, oflow_cnt, oflow,
                                           asrc, adst, bias, out, N);
}

// Round 13
// 152.692 us; speedup vs baseline: 1.0184x; 1.0184x over previous
//
#include <hip/hip_runtime.h>
#include <math.h>

#define IN_CH 128
#define OUT_CH 64
#define NEG_SLOPE 0.2f
#define CAP 64           // slots per node; mean degree 16, P(deg>64) ~ 1e-16
#define BSHIFT 8         // 256 nodes per dst-bucket -> bucket id = dst >> 8
#define BS 256           // bucket width (nodes)
#define CHUNK_EDGES 4096 // edges per bucket-role block (256 thr x 16)
#define MM_REP 2         // DIAGNOSTIC: mm role repeated (idempotent: writes h16/
                         // asrc/adst only). Surfaces k_mm_bkt above the 44us fills
                         // for counters; total-delta vs 137.6 = 1x mm-role cost.

typedef long long ll2 __attribute__((ext_vector_type(2)));
typedef int i4v __attribute__((ext_vector_type(4)));

// ---------- bf16 helpers ----------
__device__ __forceinline__ unsigned short f2bf(float f) {
    unsigned u = __float_as_uint(f);
    unsigned r = (u + 0x7FFFu + ((u >> 16) & 1u)) >> 16;   // round-nearest-even
    return (unsigned short)r;
}

// ---------- direct global->LDS 16B copy (lane i writes ldsbase + i*16) ----------
__device__ __forceinline__ void gload_lds16(const void* g, void* l) {
    __builtin_amdgcn_global_load_lds(
        (const __attribute__((address_space(1))) void*)g,
        (__attribute__((address_space(3))) void*)l, 16, 0, 0);
}

// ---------- edge dtype sniff: int64 little-endian => odd int32 words are 0 ----------
__device__ __forceinline__ bool sniff_is64(const void* edges) {
    const unsigned* up = (const unsigned*)edges;
    bool is64 = true;
#pragma unroll
    for (int k = 0; k < 16; k++) is64 = is64 && (up[2 * k + 1] == 0u);
    return is64;
}

// ---------- K1: bucket blocks (bid<nbkt) overlapped with mm blocks ----------
// R12 diagnostic results: k_agg = 18-24us, VALU-bound (VALUBusy 65%, HBM 14%) --
// NOT the 45us back-solve guess. Budget now: fill 44 + harness-reset gaps ~25 +
// {k_mm_bkt ~40, k_cs ~5, k_agg ~20}. k_mm_bkt is the big addressable unknown
// (4x its ~10us roofline) and has never shown counters -> this round x2-repeats
// the mm role (bucket role runs once; mm writes are idempotent).
__global__ __launch_bounds__(256) void k_mm_bkt(
        const float* __restrict__ x, const float* __restrict__ W,
        const float* __restrict__ att, unsigned short* __restrict__ h16,
        float* __restrict__ asrc, float* __restrict__ adst, int N,
        const void* __restrict__ edges, int E, int nbkt,
        int2* __restrict__ bucket, int bcap, int* __restrict__ bucket_cnt) {
    __shared__ float Xs[64 * IN_CH];   // 32 KB x tile (mm); bucket role aliases 2KB
    int t = threadIdx.x;
    int bid = blockIdx.x;

    if (bid < nbkt) {
        // ----- bucket role: scatter 4096 edges into per-256-node-range buckets -----
        int* lcur = (int*)Xs;          // [256]
        int* lbase = lcur + 256;       // [256]
        lcur[t] = 0;
        __syncthreads();

        int base = bid * CHUNK_EDGES + t * 16;
        bool is64 = sniff_is64(edges);
        int sv[16], dv[16], rr[16];
        int nv = E - base;
        if (nv > 16) nv = 16;
        if (nv < 0) nv = 0;
        if (nv == 16) {
            if (is64) {
                const ll2* ps = (const ll2*)((const long long*)edges + base);
                const ll2* pd = (const ll2*)((const long long*)edges + (size_t)E + base);
#pragma unroll
                for (int i = 0; i < 8; i++) {
                    ll2 v = __builtin_nontemporal_load(ps + i);
                    sv[2 * i] = (int)v.x; sv[2 * i + 1] = (int)v.y;
                }
#pragma unroll
                for (int i = 0; i < 8; i++) {
                    ll2 w = __builtin_nontemporal_load(pd + i);
                    dv[2 * i] = (int)w.x; dv[2 * i + 1] = (int)w.y;
                }
            } else {
                const i4v* ps = (const i4v*)((const int*)edges + base);
                const i4v* pd = (const i4v*)((const int*)edges + E + base);
#pragma unroll
                for (int i = 0; i < 4; i++) {
                    i4v v = __builtin_nontemporal_load(ps + i);
                    sv[4 * i] = v.x; sv[4 * i + 1] = v.y;
                    sv[4 * i + 2] = v.z; sv[4 * i + 3] = v.w;
                }
#pragma unroll
                for (int i = 0; i < 4; i++) {
                    i4v w = __builtin_nontemporal_load(pd + i);
                    dv[4 * i] = w.x; dv[4 * i + 1] = w.y;
                    dv[4 * i + 2] = w.z; dv[4 * i + 3] = w.w;
                }
            }
        } else {
            for (int i = 0; i < 16; i++) {
                if (i < nv) {
                    if (is64) {
                        sv[i] = (int)((const long long*)edges)[base + i];
                        dv[i] = (int)((const long long*)edges)[(size_t)E + base + i];
                    } else {
                        sv[i] = ((const int*)edges)[base + i];
                        dv[i] = ((const int*)edges)[E + base + i];
                    }
                } else { sv[i] = 0; dv[i] = 0; }
            }
        }
        // LDS-cursor positions (order within bucket irrelevant downstream)
#pragma unroll
        for (int i = 0; i < 16; i++)
            if (i < nv) rr[i] = atomicAdd(&lcur[(unsigned)dv[i] >> BSHIFT], 1);
        __syncthreads();
        // one device atomic per non-empty (block,bucket)
        if (t < nbkt && lcur[t] > 0) lbase[t] = atomicAdd(bucket_cnt + t, lcur[t]);
        __syncthreads();
        // place edges (contiguous run per bucket)
#pragma unroll
        for (int i = 0; i < 16; i++) {
            if (i < nv) {
                int b = (unsigned)dv[i] >> BSHIFT;
                bucket[(size_t)b * bcap + lbase[b] + rr[i]] = make_int2(sv[i], dv[i]);
            }
        }
        return;
    }

    // ----- mm role: 64 nodes/block; x tile staged in LDS; W straight from global -----
    int id = bid - nbkt;
    int cg = t & 15, g = t >> 4;
    float4 att_d = *(const float4*)&att[cg * 4];        // dst half: att[0:64]
    float4 att_s = *(const float4*)&att[64 + cg * 4];   // src half: att[64:128]
    int n0 = id * 64 + g * 4;

    for (int rep = 0; rep < MM_REP; rep++) {
        asm volatile("" ::: "memory");   // no CSE across reps: real reloads
        __syncthreads();                 // prior rep's Xs reads complete
        {
            int wv_ = t >> 6;          // wave id 0..3
            int lane = t & 63;
            int col16 = (lane & 31) * 4;                   // 16B column chunk
#pragma unroll
            for (int i = 0; i < 8; i++) {
                int seg = wv_ * 8 + i;                     // 1KB segment = 2 rows
                int row = id * 64 + seg * 2 + (lane >> 5);
                row = min(row, N - 1);                     // tail clamp
                gload_lds16(&x[(size_t)row * IN_CH + col16], &Xs[seg * 256]);
            }
        }
        __syncthreads();   // drains vmcnt (global_load_lds)

        float4 acc[4];
#pragma unroll
        for (int m = 0; m < 4; m++) acc[m] = make_float4(0.f, 0.f, 0.f, 0.f);

#pragma unroll 2
        for (int k4 = 0; k4 < IN_CH / 4; k4++) {
            float4 xv[4];
#pragma unroll
            for (int m = 0; m < 4; m++)
                xv[m] = *(const float4*)&Xs[(g * 4 + m) * IN_CH + k4 * 4];
            float4 wv[4];
#pragma unroll
            for (int j = 0; j < 4; j++)
                wv[j] = *(const float4*)&W[(k4 * 4 + j) * OUT_CH + cg * 4];
#pragma unroll
            for (int m = 0; m < 4; m++) {
                acc[m].x = fmaf(xv[m].x, wv[0].x, acc[m].x);
                acc[m].y = fmaf(xv[m].x, wv[0].y, acc[m].y);
                acc[m].z = fmaf(xv[m].x, wv[0].z, acc[m].z);
                acc[m].w = fmaf(xv[m].x, wv[0].w, acc[m].w);
                acc[m].x = fmaf(xv[m].y, wv[1].x, acc[m].x);
                acc[m].y = fmaf(xv[m].y, wv[1].y, acc[m].y);
                acc[m].z = fmaf(xv[m].y, wv[1].z, acc[m].z);
                acc[m].w = fmaf(xv[m].y, wv[1].w, acc[m].w);
                acc[m].x = fmaf(xv[m].z, wv[2].x, acc[m].x);
                acc[m].y = fmaf(xv[m].z, wv[2].y, acc[m].y);
                acc[m].z = fmaf(xv[m].z, wv[2].z, acc[m].z);
                acc[m].w = fmaf(xv[m].z, wv[2].w, acc[m].w);
                acc[m].x = fmaf(xv[m].w, wv[3].x, acc[m].x);
                acc[m].y = fmaf(xv[m].w, wv[3].y, acc[m].y);
                acc[m].z = fmaf(xv[m].w, wv[3].z, acc[m].z);
                acc[m].w = fmaf(xv[m].w, wv[3].w, acc[m].w);
            }
        }

#pragma unroll
        for (int m = 0; m < 4; m++) {
            int node = n0 + m;
            if (node < N) {
                ushort4 hv;
                hv.x = f2bf(acc[m].x);
                hv.y = f2bf(acc[m].y);
                hv.z = f2bf(acc[m].z);
                hv.w = f2bf(acc[m].w);
                *(ushort4*)&h16[(size_t)node * OUT_CH + cg * 4] = hv;
            }
            float pd = acc[m].x * att_d.x + acc[m].y * att_d.y +
                       acc[m].z * att_d.z + acc[m].w * att_d.w;
            float ps = acc[m].x * att_s.x + acc[m].y * att_s.y +
                       acc[m].z * att_s.z + acc[m].w * att_s.w;
#pragma unroll
            for (int msk = 1; msk < 16; msk <<= 1) {
                pd += __shfl_xor(pd, msk, 64);
                ps += __shfl_xor(ps, msk, 64);
            }
            if (cg == 0 && node < N) { adst[node] = pd; asrc[node] = ps; }
        }
    }
}

// ---------- K2: exclusive-bucket count+scatter (zero per-edge global atomics) -------
__global__ __launch_bounds__(256) void k_cs(
        const int2* __restrict__ bucket, int bcap,
        const int* __restrict__ bucket_cnt, int* __restrict__ counts,
        int* __restrict__ slots, int* __restrict__ oflow_cnt,
        int2* __restrict__ oflow, int N) {
    __shared__ int lcnt[256];
    int t = threadIdx.x;
    int id = blockIdx.x;
    int lo = id << BSHIFT;
    lcnt[t] = 0;
    __syncthreads();
    int cnt = bucket_cnt[id];
    const int2* mybkt = bucket + (size_t)id * bcap;
    for (int idx = t; idx < cnt; idx += 256) {
        int2 e = mybkt[idx];                       // coalesced 2KB per sweep
        int r = atomicAdd(&lcnt[e.y - lo], 1);     // LDS atomic
        if (r < CAP) {
            slots[((size_t)e.y << 6) + r] = e.x;   // exclusive, written once
        } else {
            int p2 = atomicAdd(oflow_cnt, 1);      // statistically never
            oflow[p2] = e;
        }
    }
    __syncthreads();
    int node = lo + t;
    if (node < N) counts[node] = lcnt[t];          // coalesced, line-aligned
}

// ---------- K3: softmax-aggregate (AGG_REP reverted to 1; measured 18-24us,
// VALU-bound: VALUBusy 65%, HBM 14%, Occ 59% -- R12 counters) ----------
__global__ __launch_bounds__(256) void k_agg(const unsigned short* __restrict__ h16,
                                             const int* __restrict__ slots,
                                             const int* __restrict__ counts,
                                             const int* __restrict__ oflow_cnt,
                                             const int2* __restrict__ oflow,
                                             const float* __restrict__ asrc,
                                             const float* __restrict__ adst,
                                             const float* __restrict__ bias,
                                             float* __restrict__ out, int N) {
    __shared__ float2 stage[4][64];   // wave-private
    int lane = threadIdx.x & 63;
    int wid = threadIdx.x >> 6;
    int node = blockIdx.x * 4 + wid;
    if (node >= N) return;
    int half = lane >> 5;
    int ch2 = (lane & 31) * 2;

    float aD = adst[node];
    float a = aD + asrc[node];
    a = a > 0.f ? a : NEG_SLOPE * a;
    float w_self = __expf(a);
    unsigned hv = *(const unsigned*)&h16[(size_t)node * OUT_CH + ch2];
    float wse = half ? 0.f : w_self;
    float accx = wse * __uint_as_float(hv << 16);
    float accy = wse * __uint_as_float(hv & 0xFFFF0000u);

    int c = counts[node];           // true degree (may exceed CAP)
    int cs = min(c, CAP);
    int sv = 0;
    float wv = 0.f;
    if (lane < cs) {
        sv = slots[((size_t)node << 6) + lane];   // coalesced 256B
        float av = aD + asrc[sv];                 // parallel gather (L2-hot)
        av = av > 0.f ? av : NEG_SLOPE * av;
        wv = __expf(av);
    }
    float esum_lane = wv;
    stage[wid][lane] = make_float2(__int_as_float(sv), wv);

    for (int j = 0; j < cs; j += 16) {
#pragma unroll
        for (int k = 0; k < 8; k++) {
            float2 p = stage[wid][j + 2 * k + half];   // wave-synchronous LDS
            int s = __float_as_int(p.x);
            unsigned v = *(const unsigned*)&h16[((size_t)s << 6) + ch2];
            accx = fmaf(p.y, __uint_as_float(v << 16), accx);
            accy = fmaf(p.y, __uint_as_float(v & 0xFFFF0000u), accy);
        }
    }
    accx += __shfl_xor(accx, 32, 64);
    accy += __shfl_xor(accy, 32, 64);
#pragma unroll
    for (int m = 32; m >= 1; m >>= 1) esum_lane += __shfl_xor(esum_lane, m, 64);
    float esum = esum_lane + w_self;

    int oc = *oflow_cnt;   // cold path, oc==0 in practice
    if (oc > 0) {
        for (int i = 0; i < oc; i++) {
            int2 e = oflow[i];
            if (e.y == node) {
                float av = aD + asrc[e.x];
                av = av > 0.f ? av : NEG_SLOPE * av;
                float w = __expf(av);
                esum += w;
                unsigned v = *(const unsigned*)&h16[((size_t)e.x << 6) + ch2];
                accx = fmaf(w, __uint_as_float(v << 16), accx);
                accy = fmaf(w, __uint_as_float(v & 0xFFFF0000u), accy);
            }
        }
    }

    float inv = 1.f / (esum + 1e-16f);
    float2 bv = *(const float2*)&bias[ch2];
    float vx = accx * inv + bv.x;
    float vy = accy * inv + bv.y;
    float ss = vx * vx + vy * vy;
#pragma unroll
    for (int m = 16; m >= 1; m >>= 1) ss += __shfl_xor(ss, m, 64);   // within half
    float rinv = 1.f / fmaxf(sqrtf(ss), 1e-12f);
    if (!half)
        *(float2*)&out[(size_t)node * OUT_CH + ch2] = make_float2(vx * rinv, vy * rinv);
}

extern "C" void kernel_launch(void* const* d_in, const int* in_sizes, int n_in,
                              void* d_out, int out_size, void* d_ws, size_t ws_size,
                              hipStream_t stream) {
    const float* x    = (const float*)d_in[0];
    const void*  edges = d_in[1];
    const float* W    = (const float*)d_in[2];
    const float* att  = (const float*)d_in[3];
    const float* bias = (const float*)d_in[4];
    float* out = (float*)d_out;

    const int N = in_sizes[0] / IN_CH;
    const int E = in_sizes[1] / 2;
    const int NBKT = (N + BS - 1) / BS;                  // 196 buckets (<=256)
    const int MMB = (N + 63) / 64;                       // 782 mm blocks
    const int BKB = (E + CHUNK_EDGES - 1) / CHUNK_EDGES; // 196 bucket blocks
    const int K1B = (BKB > NBKT ? BKB : NBKT);
    const int bcap = E / NBKT + 2048;                    // >30 sigma headroom

    char* ws = (char*)d_ws;
    size_t off = 0;
    auto alloc = [&](size_t bytes) -> void* {
        void* p = ws + off;
        off += bytes;
        off = (off + 255) & ~(size_t)255;
        return p;
    };
    // control block (memset target): bucket_cnt[256] | oflow_cnt @256
    int*            ctrl     = (int*)alloc(320 * 4);
    int*            counts   = (int*)alloc((size_t)N * 4);         // fully written by k2
    int*            slots    = (int*)alloc((size_t)N * CAP * 4);   // 12.8 MB
    int2*           oflow    = (int2*)alloc((size_t)65536 * 8);    // stat-impossible
    unsigned short* h16      = (unsigned short*)alloc((size_t)N * OUT_CH * 2);
    float*          asrc     = (float*)alloc((size_t)N * 4);
    float*          adst     = (float*)alloc((size_t)N * 4);
    int2*           bucket   = (int2*)alloc((size_t)NBKT * bcap * 8);  // ~9.6 MB
    int*            bucket_cnt = ctrl;
    int*            oflow_cnt  = ctrl + 256;

    hipMemsetAsync(ctrl, 0, 320 * 4, stream);
    k_mm_bkt<<<K1B + MMB, 256, 0, stream>>>(x, W, att, h16, asrc, adst, N,
                                            edges, E, NBKT, bucket, bcap,
                                            bucket_cnt);
    k_cs<<<NBKT, 256, 0, stream>>>(bucket, bcap, bucket_cnt, counts,
                                   slots, oflow_cnt, oflow, N);
    k_agg<<<(N + 3) / 4, 256, 0, stream>>>(h16, slots, counts, oflow_cnt, oflow,
                                           asrc, adst, bias, out, N);
}

// Round 14
// 137.413 us; speedup vs baseline: 1.1316x; 1.1112x over previous
//
#include <hip/hip_runtime.h>
#include <math.h>

#define IN_CH 128
#define OUT_CH 64
#define NEG_SLOPE 0.2f
#define CAP 64           // slots per node; mean degree 16, P(deg>64) ~ 1e-16
#define BSHIFT 8         // 256 nodes per dst-bucket -> bucket id = dst >> 8
#define BS 256           // bucket width (nodes)
#define CHUNK_EDGES 4096 // edges per bucket-role block (256 thr x 16)

typedef long long ll2 __attribute__((ext_vector_type(2)));
typedef int i4v __attribute__((ext_vector_type(4)));

// ---------- bf16 helpers ----------
__device__ __forceinline__ unsigned short f2bf(float f) {
    unsigned u = __float_as_uint(f);
    unsigned r = (u + 0x7FFFu + ((u >> 16) & 1u)) >> 16;   // round-nearest-even
    return (unsigned short)r;
}

// ---------- direct global->LDS 16B copy (lane i writes ldsbase + i*16) ----------
__device__ __forceinline__ void gload_lds16(const void* g, void* l) {
    __builtin_amdgcn_global_load_lds(
        (const __attribute__((address_space(1))) void*)g,
        (__attribute__((address_space(3))) void*)l, 16, 0, 0);
}

// ---------- edge dtype sniff: int64 little-endian => odd int32 words are 0 ----------
__device__ __forceinline__ bool sniff_is64(const void* edges) {
    const unsigned* up = (const unsigned*)edges;
    bool is64 = true;
#pragma unroll
    for (int k = 0; k < 16; k++) is64 = is64 && (up[2 * k + 1] == 0u);
    return is64;
}

// ---------- K1: bucket blocks (bid<nbkt) overlapped with mm blocks ----------
// R13 diagnostic (MM_REP=2): mm-role marginal = 15.1us L3-hot (compute floor, not
// HBM), and SQ_LDS_BANK_CONFLICT = 3.3M -- the Xs read has row stride 512B == 0
// mod 32 banks, so the 4 distinct per-wave row addresses (g=0..3) start at the
// same bank: 4-way conflict on every ds_read_b128 (~1.58x LDS time, m136).
// Fix (rule #21, both-sides-or-neither): gload_lds writes LINEARLY, so the swizzle
// is applied on the SOURCE -- lane writing LDS slot s of tile row r fetches global
// chunk s^(r&31); reader addresses chunk k4 at slot k4^(row&31). Conflicting rows
// {m,4+m,8+m,12+m} then map to bank pairs {b, b^16} -> 2-way, which is free.
// Source stays coalesced (permutation within each aligned 512B row). MM_REP
// reverted to 1.
__global__ __launch_bounds__(256) void k_mm_bkt(
        const float* __restrict__ x, const float* __restrict__ W,
        const float* __restrict__ att, unsigned short* __restrict__ h16,
        float* __restrict__ asrc, float* __restrict__ adst, int N,
        const void* __restrict__ edges, int E, int nbkt,
        int2* __restrict__ bucket, int bcap, int* __restrict__ bucket_cnt) {
    __shared__ float Xs[64 * IN_CH];   // 32 KB x tile (mm); bucket role aliases 2KB
    int t = threadIdx.x;
    int bid = blockIdx.x;

    if (bid < nbkt) {
        // ----- bucket role: scatter 4096 edges into per-256-node-range buckets -----
        int* lcur = (int*)Xs;          // [256]
        int* lbase = lcur + 256;       // [256]
        lcur[t] = 0;
        __syncthreads();

        int base = bid * CHUNK_EDGES + t * 16;
        bool is64 = sniff_is64(edges);
        int sv[16], dv[16], rr[16];
        int nv = E - base;
        if (nv > 16) nv = 16;
        if (nv < 0) nv = 0;
        if (nv == 16) {
            if (is64) {
                const ll2* ps = (const ll2*)((const long long*)edges + base);
                const ll2* pd = (const ll2*)((const long long*)edges + (size_t)E + base);
#pragma unroll
                for (int i = 0; i < 8; i++) {
                    ll2 v = __builtin_nontemporal_load(ps + i);
                    sv[2 * i] = (int)v.x; sv[2 * i + 1] = (int)v.y;
                }
#pragma unroll
                for (int i = 0; i < 8; i++) {
                    ll2 w = __builtin_nontemporal_load(pd + i);
                    dv[2 * i] = (int)w.x; dv[2 * i + 1] = (int)w.y;
                }
            } else {
                const i4v* ps = (const i4v*)((const int*)edges + base);
                const i4v* pd = (const i4v*)((const int*)edges + E + base);
#pragma unroll
                for (int i = 0; i < 4; i++) {
                    i4v v = __builtin_nontemporal_load(ps + i);
                    sv[4 * i] = v.x; sv[4 * i + 1] = v.y;
                    sv[4 * i + 2] = v.z; sv[4 * i + 3] = v.w;
                }
#pragma unroll
                for (int i = 0; i < 4; i++) {
                    i4v w = __builtin_nontemporal_load(pd + i);
                    dv[4 * i] = w.x; dv[4 * i + 1] = w.y;
                    dv[4 * i + 2] = w.z; dv[4 * i + 3] = w.w;
                }
            }
        } else {
            for (int i = 0; i < 16; i++) {
                if (i < nv) {
                    if (is64) {
                        sv[i] = (int)((const long long*)edges)[base + i];
                        dv[i] = (int)((const long long*)edges)[(size_t)E + base + i];
                    } else {
                        sv[i] = ((const int*)edges)[base + i];
                        dv[i] = ((const int*)edges)[E + base + i];
                    }
                } else { sv[i] = 0; dv[i] = 0; }
            }
        }
        // LDS-cursor positions (order within bucket irrelevant downstream)
#pragma unroll
        for (int i = 0; i < 16; i++)
            if (i < nv) rr[i] = atomicAdd(&lcur[(unsigned)dv[i] >> BSHIFT], 1);
        __syncthreads();
        // one device atomic per non-empty (block,bucket)
        if (t < nbkt && lcur[t] > 0) lbase[t] = atomicAdd(bucket_cnt + t, lcur[t]);
        __syncthreads();
        // place edges (contiguous run per bucket)
#pragma unroll
        for (int i = 0; i < 16; i++) {
            if (i < nv) {
                int b = (unsigned)dv[i] >> BSHIFT;
                bucket[(size_t)b * bcap + lbase[b] + rr[i]] = make_int2(sv[i], dv[i]);
            }
        }
        return;
    }

    // ----- mm role: 64 nodes/block; x tile staged in LDS (XOR-swizzled via
    // pre-swizzled source); W straight from global -----
    int id = bid - nbkt;
    {
        int wv_ = t >> 6;          // wave id 0..3
        int lane = t & 63;
        int slot = lane & 31;      // 16B chunk slot within a 512B row
#pragma unroll
        for (int i = 0; i < 8; i++) {
            int seg = wv_ * 8 + i;                 // 1KB segment = 2 rows
            int trow = seg * 2 + (lane >> 5);      // tile-local row 0..63
            int grow = min(id * 64 + trow, N - 1); // tail clamp (dup row N-1)
            int c = slot ^ (trow & 31);            // pre-swizzled source chunk
            gload_lds16(&x[(size_t)grow * IN_CH + c * 4], &Xs[seg * 256]);
        }
    }
    int cg = t & 15, g = t >> 4;
    float4 att_d = *(const float4*)&att[cg * 4];        // dst half: att[0:64]
    float4 att_s = *(const float4*)&att[64 + cg * 4];   // src half: att[64:128]
    __syncthreads();   // drains vmcnt (global_load_lds)

    int n0 = id * 64 + g * 4;

    float4 acc[4];
#pragma unroll
    for (int m = 0; m < 4; m++) acc[m] = make_float4(0.f, 0.f, 0.f, 0.f);

#pragma unroll 2
    for (int k4 = 0; k4 < IN_CH / 4; k4++) {
        float4 xv[4];
#pragma unroll
        for (int m = 0; m < 4; m++) {
            int row = g * 4 + m;
            xv[m] = *(const float4*)&Xs[row * IN_CH + ((k4 ^ (row & 31)) << 2)];
        }
        float4 wv[4];
#pragma unroll
        for (int j = 0; j < 4; j++)
            wv[j] = *(const float4*)&W[(k4 * 4 + j) * OUT_CH + cg * 4];
#pragma unroll
        for (int m = 0; m < 4; m++) {
            acc[m].x = fmaf(xv[m].x, wv[0].x, acc[m].x);
            acc[m].y = fmaf(xv[m].x, wv[0].y, acc[m].y);
            acc[m].z = fmaf(xv[m].x, wv[0].z, acc[m].z);
            acc[m].w = fmaf(xv[m].x, wv[0].w, acc[m].w);
            acc[m].x = fmaf(xv[m].y, wv[1].x, acc[m].x);
            acc[m].y = fmaf(xv[m].y, wv[1].y, acc[m].y);
            acc[m].z = fmaf(xv[m].y, wv[1].z, acc[m].z);
            acc[m].w = fmaf(xv[m].y, wv[1].w, acc[m].w);
            acc[m].x = fmaf(xv[m].z, wv[2].x, acc[m].x);
            acc[m].y = fmaf(xv[m].z, wv[2].y, acc[m].y);
            acc[m].z = fmaf(xv[m].z, wv[2].z, acc[m].z);
            acc[m].w = fmaf(xv[m].z, wv[2].w, acc[m].w);
            acc[m].x = fmaf(xv[m].w, wv[3].x, acc[m].x);
            acc[m].y = fmaf(xv[m].w, wv[3].y, acc[m].y);
            acc[m].z = fmaf(xv[m].w, wv[3].z, acc[m].z);
            acc[m].w = fmaf(xv[m].w, wv[3].w, acc[m].w);
        }
    }

#pragma unroll
    for (int m = 0; m < 4; m++) {
        int node = n0 + m;
        if (node < N) {
            ushort4 hv;
            hv.x = f2bf(acc[m].x);
            hv.y = f2bf(acc[m].y);
            hv.z = f2bf(acc[m].z);
            hv.w = f2bf(acc[m].w);
            *(ushort4*)&h16[(size_t)node * OUT_CH + cg * 4] = hv;
        }
        float pd = acc[m].x * att_d.x + acc[m].y * att_d.y +
                   acc[m].z * att_d.z + acc[m].w * att_d.w;
        float ps = acc[m].x * att_s.x + acc[m].y * att_s.y +
                   acc[m].z * att_s.z + acc[m].w * att_s.w;
#pragma unroll
        for (int msk = 1; msk < 16; msk <<= 1) {
            pd += __shfl_xor(pd, msk, 64);
            ps += __shfl_xor(ps, msk, 64);
        }
        if (cg == 0 && node < N) { adst[node] = pd; asrc[node] = ps; }
    }
}

// ---------- K2: exclusive-bucket count+scatter (zero per-edge global atomics) -------
__global__ __launch_bounds__(256) void k_cs(
        const int2* __restrict__ bucket, int bcap,
        const int* __restrict__ bucket_cnt, int* __restrict__ counts,
        int* __restrict__ slots, int* __restrict__ oflow_cnt,
        int2* __restrict__ oflow, int N) {
    __shared__ int lcnt[256];
    int t = threadIdx.x;
    int id = blockIdx.x;
    int lo = id << BSHIFT;
    lcnt[t] = 0;
    __syncthreads();
    int cnt = bucket_cnt[id];
    const int2* mybkt = bucket + (size_t)id * bcap;
    for (int idx = t; idx < cnt; idx += 256) {
        int2 e = mybkt[idx];                       // coalesced 2KB per sweep
        int r = atomicAdd(&lcnt[e.y - lo], 1);     // LDS atomic
        if (r < CAP) {
            slots[((size_t)e.y << 6) + r] = e.x;   // exclusive, written once
        } else {
            int p2 = atomicAdd(oflow_cnt, 1);      // statistically never
            oflow[p2] = e;
        }
    }
    __syncthreads();
    int node = lo + t;
    if (node < N) counts[node] = lcnt[t];          // coalesced, line-aligned
}

// ---------- K3: softmax-aggregate (measured R12: 18-24us, VALU-bound --
// VALUBusy 65%, HBM 14%, Occ 59%) ----------
__global__ __launch_bounds__(256) void k_agg(const unsigned short* __restrict__ h16,
                                             const int* __restrict__ slots,
                                             const int* __restrict__ counts,
                                             const int* __restrict__ oflow_cnt,
                                             const int2* __restrict__ oflow,
                                             const float* __restrict__ asrc,
                                             const float* __restrict__ adst,
                                             const float* __restrict__ bias,
                                             float* __restrict__ out, int N) {
    __shared__ float2 stage[4][64];   // wave-private
    int lane = threadIdx.x & 63;
    int wid = threadIdx.x >> 6;
    int node = blockIdx.x * 4 + wid;
    if (node >= N) return;
    int half = lane >> 5;
    int ch2 = (lane & 31) * 2;

    float aD = adst[node];
    float a = aD + asrc[node];
    a = a > 0.f ? a : NEG_SLOPE * a;
    float w_self = __expf(a);
    unsigned hv = *(const unsigned*)&h16[(size_t)node * OUT_CH + ch2];
    float wse = half ? 0.f : w_self;
    float accx = wse * __uint_as_float(hv << 16);
    float accy = wse * __uint_as_float(hv & 0xFFFF0000u);

    int c = counts[node];           // true degree (may exceed CAP)
    int cs = min(c, CAP);
    int sv = 0;
    float wv = 0.f;
    if (lane < cs) {
        sv = slots[((size_t)node << 6) + lane];   // coalesced 256B
        float av = aD + asrc[sv];                 // parallel gather (L2-hot)
        av = av > 0.f ? av : NEG_SLOPE * av;
        wv = __expf(av);
    }
    float esum_lane = wv;
    stage[wid][lane] = make_float2(__int_as_float(sv), wv);

    for (int j = 0; j < cs; j += 16) {
#pragma unroll
        for (int k = 0; k < 8; k++) {
            float2 p = stage[wid][j + 2 * k + half];   // wave-synchronous LDS
            int s = __float_as_int(p.x);
            unsigned v = *(const unsigned*)&h16[((size_t)s << 6) + ch2];
            accx = fmaf(p.y, __uint_as_float(v << 16), accx);
            accy = fmaf(p.y, __uint_as_float(v & 0xFFFF0000u), accy);
        }
    }
    accx += __shfl_xor(accx, 32, 64);
    accy += __shfl_xor(accy, 32, 64);
#pragma unroll
    for (int m = 32; m >= 1; m >>= 1) esum_lane += __shfl_xor(esum_lane, m, 64);
    float esum = esum_lane + w_self;

    int oc = *oflow_cnt;   // cold path, oc==0 in practice
    if (oc > 0) {
        for (int i = 0; i < oc; i++) {
            int2 e = oflow[i];
            if (e.y == node) {
                float av = aD + asrc[e.x];
                av = av > 0.f ? av : NEG_SLOPE * av;
                float w = __expf(av);
                esum += w;
                unsigned v = *(const unsigned*)&h16[((size_t)e.x << 6) + ch2];
                accx = fmaf(w, __uint_as_float(v << 16), accx);
                accy = fmaf(w, __uint_as_float(v & 0xFFFF0000u), accy);
            }
        }
    }

    float inv = 1.f / (esum + 1e-16f);
    float2 bv = *(const float2*)&bias[ch2];
    float vx = accx * inv + bv.x;
    float vy = accy * inv + bv.y;
    float ss = vx * vx + vy * vy;
#pragma unroll
    for (int m = 16; m >= 1; m >>= 1) ss += __shfl_xor(ss, m, 64);   // within half
    float rinv = 1.f / fmaxf(sqrtf(ss), 1e-12f);
    if (!half)
        *(float2*)&out[(size_t)node * OUT_CH + ch2] = make_float2(vx * rinv, vy * rinv);
}

extern "C" void kernel_launch(void* const* d_in, const int* in_sizes, int n_in,
                              void* d_out, int out_size, void* d_ws, size_t ws_size,
                              hipStream_t stream) {
    const float* x    = (const float*)d_in[0];
    const void*  edges = d_in[1];
    const float* W    = (const float*)d_in[2];
    const float* att  = (const float*)d_in[3];
    const float* bias = (const float*)d_in[4];
    float* out = (float*)d_out;

    const int N = in_sizes[0] / IN_CH;
    const int E = in_sizes[1] / 2;
    const int NBKT = (N + BS - 1) / BS;                  // 196 buckets (<=256)
    const int MMB = (N + 63) / 64;                       // 782 mm blocks
    const int BKB = (E + CHUNK_EDGES - 1) / CHUNK_EDGES; // 196 bucket blocks
    const int K1B = (BKB > NBKT ? BKB : NBKT);
    const int bcap = E / NBKT + 2048;                    // >30 sigma headroom

    char* ws = (char*)d_ws;
    size_t off = 0;
    auto alloc = [&](size_t bytes) -> void* {
        void* p = ws + off;
        off += bytes;
        off = (off + 255) & ~(size_t)255;
        return p;
    };
    // control block (memset target): bucket_cnt[256] | oflow_cnt @256
    int*            ctrl     = (int*)alloc(320 * 4);
    int*            counts   = (int*)alloc((size_t)N * 4);         // fully written by k2
    int*            slots    = (int*)alloc((size_t)N * CAP * 4);   // 12.8 MB
    int2*           oflow    = (int2*)alloc((size_t)65536 * 8);    // stat-impossible
    unsigned short* h16      = (unsigned short*)alloc((size_t)N * OUT_CH * 2);
    float*          asrc     = (float*)alloc((size_t)N * 4);
    float*          adst     = (float*)alloc((size_t)N * 4);
    int2*           bucket   = (int2*)alloc((size_t)NBKT * bcap * 8);  // ~9.6 MB
    int*            bucket_cnt = ctrl;
    int*            oflow_cnt  = ctrl + 256;

    hipMemsetAsync(ctrl, 0, 320 * 4, stream);
    k_mm_bkt<<<K1B + MMB, 256, 0, stream>>>(x, W, att, h16, asrc, adst, N,
                                            edges, E, NBKT, bucket, bcap,
                                            bucket_cnt);
    k_cs<<<NBKT, 256, 0, stream>>>(bucket, bcap, bucket_cnt, counts,
                                   slots, oflow_cnt, oflow, N);
    k_agg<<<(N + 3) / 4, 256, 0, stream>>>(h16, slots, counts, oflow_cnt, oflow,
                                           asrc, adst, bias, out, N);
}